// Round 1
// baseline (985.485 us; speedup 1.0000x reference)
//
#include <hip/hip_runtime.h>
#include <hip/hip_bf16.h>

#define N_NODES 100000
#define N_USERS 200000
#define N_ITEMS 200000
#define KNEI 24
#define E 64
#define F 128

// ---- workspace layout (bytes) ----
// i_proj bf16 [N_ITEMS][64] : off 0          size 25,600,000
// i_att  bf16 [N_ITEMS][64] : off 25,600,000 size 25,600,000
// q_att  bf16 [N_NODES][64] : off 51,200,000 size 12,800,000
// winner int  [N_USERS]     : off 64,000,000 size    800,000
// total 64.8 MB

__device__ inline unsigned pk_bf16x2(float a, float b) {
    __hip_bfloat16 ha = __float2bfloat16(a), hb = __float2bfloat16(b);
    unsigned short ua = *reinterpret_cast<unsigned short*>(&ha);
    unsigned short ub = *reinterpret_cast<unsigned short*>(&hb);
    return (unsigned)ua | ((unsigned)ub << 16);
}

__device__ inline void store_bf16_row64(__hip_bfloat16* dst, const float* v) {
    #pragma unroll
    for (int j0 = 0; j0 < E; j0 += 8) {
        uint4 u;
        u.x = pk_bf16x2(v[j0 + 0], v[j0 + 1]);
        u.y = pk_bf16x2(v[j0 + 2], v[j0 + 3]);
        u.z = pk_bf16x2(v[j0 + 4], v[j0 + 5]);
        u.w = pk_bf16x2(v[j0 + 6], v[j0 + 7]);
        *reinterpret_cast<uint4*>(reinterpret_cast<char*>(dst) + (size_t)j0 * 2) = u;
    }
}

// ---- winner: last occurrence of each user id wins the scatter ----
__global__ __launch_bounds__(256) void k_winner(const int* __restrict__ nodes,
                                                int* __restrict__ winner) {
    int i = blockIdx.x * 256 + threadIdx.x;
    if (i < N_NODES) atomicMax(&winner[nodes[i]], i);
}

// ---- per-item: i_proj = i_weight@iW + ib ; i_att = i_proj@aW1[:64] + ab1 ----
__global__ __launch_bounds__(256, 2) void k_item(const float* __restrict__ iwt,
                                                 const float* __restrict__ iW,
                                                 const float* __restrict__ ib,
                                                 const float* __restrict__ aW1,
                                                 const float* __restrict__ ab1,
                                                 __hip_bfloat16* __restrict__ iproj,
                                                 __hip_bfloat16* __restrict__ iatt) {
    int it = blockIdx.x * 256 + threadIdx.x;
    if (it >= N_ITEMS) return;
    const float4* row = reinterpret_cast<const float4*>(iwt + (size_t)it * F);

    float p[E];
    #pragma unroll
    for (int j = 0; j < E; j++) p[j] = ib[j];
    for (int f4 = 0; f4 < F / 4; ++f4) {
        float4 v = row[f4];
        const float* w = iW + (size_t)f4 * 4 * E;   // uniform address -> s_load
        #pragma unroll
        for (int j = 0; j < E; j++) p[j] = fmaf(v.x, w[j], p[j]);
        #pragma unroll
        for (int j = 0; j < E; j++) p[j] = fmaf(v.y, w[E + j], p[j]);
        #pragma unroll
        for (int j = 0; j < E; j++) p[j] = fmaf(v.z, w[2 * E + j], p[j]);
        #pragma unroll
        for (int j = 0; j < E; j++) p[j] = fmaf(v.w, w[3 * E + j], p[j]);
    }
    store_bf16_row64(iproj + (size_t)it * E, p);

    float a[E];
    #pragma unroll
    for (int j = 0; j < E; j++) a[j] = ab1[j];
    #pragma unroll
    for (int c = 0; c < E; c++) {
        float v = p[c];
        const float* w = aW1 + (size_t)c * E;       // compile-time offsets
        #pragma unroll
        for (int j = 0; j < E; j++) a[j] = fmaf(v, w[j], a[j]);
    }
    store_bf16_row64(iatt + (size_t)it * E, a);
}

// ---- per-node: nodes_fea = u_weight[nodes]@uW + ub (f32 out);
//                q_att = (nodes_fea + n_feature)@aW1[64:] (bf16 ws) ----
__global__ __launch_bounds__(256, 2) void k_node(const int* __restrict__ nodes,
                                                 const float* __restrict__ nfeat,
                                                 const float* __restrict__ uwt,
                                                 const float* __restrict__ uW,
                                                 const float* __restrict__ ub,
                                                 const float* __restrict__ aW1,
                                                 float* __restrict__ out_nf,
                                                 __hip_bfloat16* __restrict__ qatt) {
    int n = blockIdx.x * 256 + threadIdx.x;
    if (n >= N_NODES) return;
    int un = nodes[n];
    const float4* row = reinterpret_cast<const float4*>(uwt + (size_t)un * F);

    float p[E];
    #pragma unroll
    for (int j = 0; j < E; j++) p[j] = ub[j];
    for (int f4 = 0; f4 < F / 4; ++f4) {
        float4 v = row[f4];
        const float* w = uW + (size_t)f4 * 4 * E;
        #pragma unroll
        for (int j = 0; j < E; j++) p[j] = fmaf(v.x, w[j], p[j]);
        #pragma unroll
        for (int j = 0; j < E; j++) p[j] = fmaf(v.y, w[E + j], p[j]);
        #pragma unroll
        for (int j = 0; j < E; j++) p[j] = fmaf(v.z, w[2 * E + j], p[j]);
        #pragma unroll
        for (int j = 0; j < E; j++) p[j] = fmaf(v.w, w[3 * E + j], p[j]);
    }
    // write nodes_fea (f32, output 0)
    float* o = out_nf + (size_t)n * E;
    #pragma unroll
    for (int j0 = 0; j0 < E; j0 += 4) {
        float4 s = make_float4(p[j0], p[j0 + 1], p[j0 + 2], p[j0 + 3]);
        *reinterpret_cast<float4*>(o + j0) = s;
    }
    // q = nodes_fea + n_feature[n]
    const float4* nf4 = reinterpret_cast<const float4*>(nfeat + (size_t)n * E);
    #pragma unroll
    for (int j0 = 0; j0 < E; j0 += 4) {
        float4 v = nf4[j0 / 4];
        p[j0] += v.x; p[j0 + 1] += v.y; p[j0 + 2] += v.z; p[j0 + 3] += v.w;
    }
    // q_att = q @ aW1[64:128,:]   (no bias here; ab1 lives in i_att)
    float a[E];
    #pragma unroll
    for (int j = 0; j < E; j++) a[j] = 0.f;
    #pragma unroll
    for (int c = 0; c < E; c++) {
        float v = p[c];
        const float* w = aW1 + (size_t)(E + c) * E;
        #pragma unroll
        for (int j = 0; j < E; j++) a[j] = fmaf(v, w[j], a[j]);
    }
    store_bf16_row64(qatt + (size_t)n * E, a);
}

__device__ inline float rdlane_f(float v, int l) {
    return __uint_as_float(__builtin_amdgcn_readlane(__float_as_uint(v), l));
}

// ---- attention: wave per node, lane = feature dim ----
__global__ __launch_bounds__(256, 2) void k_att(const int* __restrict__ nodes,
                                                const int* __restrict__ nidx,
                                                const __hip_bfloat16* __restrict__ iproj,
                                                const __hip_bfloat16* __restrict__ iatt,
                                                const __hip_bfloat16* __restrict__ qatt,
                                                const float* __restrict__ aW2,
                                                const float* __restrict__ ab2,
                                                const float* __restrict__ aW3,
                                                const int* __restrict__ winner,
                                                float* __restrict__ outE) {
    int wave = threadIdx.x >> 6;
    int lane = threadIdx.x & 63;
    int n = blockIdx.x * 4 + wave;   // grid = N_NODES/4 exactly

    // lane j holds column j of aW2 (64 regs), plus aW3[j], ab2[j]
    float w2c[E];
    #pragma unroll
    for (int c = 0; c < E; c++) w2c[c] = aW2[(size_t)c * E + lane];
    float w3 = aW3[lane];
    float b2 = ab2[lane];
    float qa = __bfloat162float(qatt[(size_t)n * E + lane]);
    int idxv = (lane < KNEI) ? nidx[(size_t)n * KNEI + lane] : 0;

    // h1[k][lane] = relu(i_att[idx_k][lane] + q_att[n][lane])
    float h1[KNEI];
    #pragma unroll
    for (int k = 0; k < KNEI; k++) {
        int sidx = __builtin_amdgcn_readlane(idxv, k);
        float v = __bfloat162float(iatt[(size_t)sidx * E + lane]);
        h1[k] = fmaxf(v + qa, 0.f);
    }

    // scores: h2 = relu(h1@aW2 + ab2); score_k = h2 . aW3  (ab3 dropped: softmax-invariant)
    float myscore = -1e30f;
    #pragma unroll
    for (int k = 0; k < KNEI; k++) {
        float a0 = b2, a1 = 0.f, a2 = 0.f, a3 = 0.f;
        #pragma unroll
        for (int c = 0; c < E; c += 4) {
            a0 = fmaf(rdlane_f(h1[k], c + 0), w2c[c + 0], a0);
            a1 = fmaf(rdlane_f(h1[k], c + 1), w2c[c + 1], a1);
            a2 = fmaf(rdlane_f(h1[k], c + 2), w2c[c + 2], a2);
            a3 = fmaf(rdlane_f(h1[k], c + 3), w2c[c + 3], a3);
        }
        float h2 = fmaxf((a0 + a1) + (a2 + a3), 0.f);
        float part = h2 * w3;
        #pragma unroll
        for (int m = 1; m < 64; m <<= 1) part += __shfl_xor(part, m);
        myscore = (lane == k) ? part : myscore;
    }

    // softmax over k (lanes 0..23)
    float mx = myscore;
    #pragma unroll
    for (int m = 1; m < 64; m <<= 1) mx = fmaxf(mx, __shfl_xor(mx, m));
    float e = (lane < KNEI) ? __expf(myscore - mx) : 0.f;
    float s = e;
    #pragma unroll
    for (int m = 1; m < 64; m <<= 1) s += __shfl_xor(s, m);
    float wgt = e / s;

    // emb[lane] = sum_k wgt_k * i_proj[idx_k][lane]
    float emb = 0.f;
    #pragma unroll
    for (int k = 0; k < KNEI; k++) {
        int sidx = __builtin_amdgcn_readlane(idxv, k);
        float wk = rdlane_f(wgt, k);
        emb = fmaf(wk, __bfloat162float(iproj[(size_t)sidx * E + lane]), emb);
    }

    int un = nodes[n];                 // uniform per wave
    if (winner[un] == n) outE[(size_t)un * E + lane] = emb;
}

extern "C" void kernel_launch(void* const* d_in, const int* in_sizes, int n_in,
                              void* d_out, int out_size, void* d_ws, size_t ws_size,
                              hipStream_t stream) {
    const int*   nodes = (const int*)d_in[0];
    const float* nfeat = (const float*)d_in[1];
    const int*   nidx  = (const int*)d_in[2];
    const float* uwt   = (const float*)d_in[3];
    const float* iwt   = (const float*)d_in[4];
    const float* uW    = (const float*)d_in[5];
    const float* ub    = (const float*)d_in[6];
    const float* iW    = (const float*)d_in[7];
    const float* ib    = (const float*)d_in[8];
    const float* aW1   = (const float*)d_in[9];
    const float* ab1   = (const float*)d_in[10];
    const float* aW2   = (const float*)d_in[11];
    const float* ab2   = (const float*)d_in[12];
    const float* aW3   = (const float*)d_in[13];
    // d_in[14] = ab3: softmax-shift-invariant, unused

    float* out_nf  = (float*)d_out;
    float* out_emb = out_nf + (size_t)N_NODES * E;

    char* ws = (char*)d_ws;
    __hip_bfloat16* iproj = (__hip_bfloat16*)(ws);
    __hip_bfloat16* iatt  = (__hip_bfloat16*)(ws + 25600000);
    __hip_bfloat16* qatt  = (__hip_bfloat16*)(ws + 51200000);
    int*            winner = (int*)(ws + 64000000);

    hipMemsetAsync(winner, 0xFF, (size_t)N_USERS * sizeof(int), stream);          // -1
    hipMemsetAsync(out_emb, 0, (size_t)N_USERS * E * sizeof(float), stream);

    k_winner<<<(N_NODES + 255) / 256, 256, 0, stream>>>(nodes, winner);
    k_item<<<(N_ITEMS + 255) / 256, 256, 0, stream>>>(iwt, iW, ib, aW1, ab1, iproj, iatt);
    k_node<<<(N_NODES + 255) / 256, 256, 0, stream>>>(nodes, nfeat, uwt, uW, ub, aW1,
                                                      out_nf, qatt);
    k_att<<<N_NODES / 4, 256, 0, stream>>>(nodes, nidx, iproj, iatt, qatt,
                                           aW2, ab2, aW3, winner, out_emb);
}

// Round 2
// 523.927 us; speedup vs baseline: 1.8810x; 1.8810x over previous
//
#include <hip/hip_runtime.h>
#include <hip/hip_bf16.h>

#define N_NODES 100000
#define N_USERS 200000
#define N_ITEMS 200000
#define KNEI 24
#define E 64
#define F 128

typedef __attribute__((ext_vector_type(8))) short bf16x8;
typedef __attribute__((ext_vector_type(4))) float f32x4;

// ---- workspace layout (bytes) ----
// i_proj bf16 [N_ITEMS][64] : off 0          size 25,600,000
// i_att  bf16 [N_ITEMS][64] : off 25,600,000 size 25,600,000
// q_att  bf16 [N_NODES][64] : off 51,200,000 size 12,800,000
// winner int  [N_USERS]     : off 64,000,000 size    800,000

__device__ inline float bf2f(short s) {
    unsigned u = ((unsigned)(unsigned short)s) << 16;
    return __uint_as_float(u);
}
__device__ inline short f2bf(float f) {
    __hip_bfloat16 h = __float2bfloat16(f);
    return *reinterpret_cast<short*>(&h);
}
__device__ inline float rdlane_f(float v, int l) {
    return __uint_as_float(__builtin_amdgcn_readlane(__float_as_uint(v), l));
}

__device__ inline unsigned pk_bf16x2(float a, float b) {
    __hip_bfloat16 ha = __float2bfloat16(a), hb = __float2bfloat16(b);
    unsigned short ua = *reinterpret_cast<unsigned short*>(&ha);
    unsigned short ub = *reinterpret_cast<unsigned short*>(&hb);
    return (unsigned)ua | ((unsigned)ub << 16);
}
__device__ inline void store_bf16_row64(__hip_bfloat16* dst, const float* v) {
    #pragma unroll
    for (int j0 = 0; j0 < E; j0 += 8) {
        uint4 u;
        u.x = pk_bf16x2(v[j0 + 0], v[j0 + 1]);
        u.y = pk_bf16x2(v[j0 + 2], v[j0 + 3]);
        u.z = pk_bf16x2(v[j0 + 4], v[j0 + 5]);
        u.w = pk_bf16x2(v[j0 + 6], v[j0 + 7]);
        *reinterpret_cast<uint4*>(reinterpret_cast<char*>(dst) + (size_t)j0 * 2) = u;
    }
}

// ---- winner: last occurrence of each user id wins the scatter ----
__global__ __launch_bounds__(256) void k_winner(const int* __restrict__ nodes,
                                                int* __restrict__ winner) {
    int i = blockIdx.x * 256 + threadIdx.x;
    if (i < N_NODES) atomicMax(&winner[nodes[i]], i);
}

// ---- per-item: i_proj = i_weight@iW + ib ; i_att = i_proj@aW1[:64] + ab1 ----
__global__ __launch_bounds__(256, 2) void k_item(const float* __restrict__ iwt,
                                                 const float* __restrict__ iW,
                                                 const float* __restrict__ ib,
                                                 const float* __restrict__ aW1,
                                                 const float* __restrict__ ab1,
                                                 __hip_bfloat16* __restrict__ iproj,
                                                 __hip_bfloat16* __restrict__ iatt) {
    int it = blockIdx.x * 256 + threadIdx.x;
    if (it >= N_ITEMS) return;
    const float4* row = reinterpret_cast<const float4*>(iwt + (size_t)it * F);

    float p[E];
    #pragma unroll
    for (int j = 0; j < E; j++) p[j] = ib[j];
    for (int f4 = 0; f4 < F / 4; ++f4) {
        float4 v = row[f4];
        const float* w = iW + (size_t)f4 * 4 * E;
        #pragma unroll
        for (int j = 0; j < E; j++) p[j] = fmaf(v.x, w[j], p[j]);
        #pragma unroll
        for (int j = 0; j < E; j++) p[j] = fmaf(v.y, w[E + j], p[j]);
        #pragma unroll
        for (int j = 0; j < E; j++) p[j] = fmaf(v.z, w[2 * E + j], p[j]);
        #pragma unroll
        for (int j = 0; j < E; j++) p[j] = fmaf(v.w, w[3 * E + j], p[j]);
    }
    store_bf16_row64(iproj + (size_t)it * E, p);

    float a[E];
    #pragma unroll
    for (int j = 0; j < E; j++) a[j] = ab1[j];
    #pragma unroll
    for (int c = 0; c < E; c++) {
        float v = p[c];
        const float* w = aW1 + (size_t)c * E;
        #pragma unroll
        for (int j = 0; j < E; j++) a[j] = fmaf(v, w[j], a[j]);
    }
    store_bf16_row64(iatt + (size_t)it * E, a);
}

// ---- per-node: nodes_fea = u_weight[nodes]@uW + ub (f32 out);
//                q_att = (nodes_fea + n_feature)@aW1[64:] (bf16 ws) ----
__global__ __launch_bounds__(256, 2) void k_node(const int* __restrict__ nodes,
                                                 const float* __restrict__ nfeat,
                                                 const float* __restrict__ uwt,
                                                 const float* __restrict__ uW,
                                                 const float* __restrict__ ub,
                                                 const float* __restrict__ aW1,
                                                 float* __restrict__ out_nf,
                                                 __hip_bfloat16* __restrict__ qatt) {
    int n = blockIdx.x * 256 + threadIdx.x;
    if (n >= N_NODES) return;
    int un = nodes[n];
    const float4* row = reinterpret_cast<const float4*>(uwt + (size_t)un * F);

    float p[E];
    #pragma unroll
    for (int j = 0; j < E; j++) p[j] = ub[j];
    for (int f4 = 0; f4 < F / 4; ++f4) {
        float4 v = row[f4];
        const float* w = uW + (size_t)f4 * 4 * E;
        #pragma unroll
        for (int j = 0; j < E; j++) p[j] = fmaf(v.x, w[j], p[j]);
        #pragma unroll
        for (int j = 0; j < E; j++) p[j] = fmaf(v.y, w[E + j], p[j]);
        #pragma unroll
        for (int j = 0; j < E; j++) p[j] = fmaf(v.z, w[2 * E + j], p[j]);
        #pragma unroll
        for (int j = 0; j < E; j++) p[j] = fmaf(v.w, w[3 * E + j], p[j]);
    }
    float* o = out_nf + (size_t)n * E;
    #pragma unroll
    for (int j0 = 0; j0 < E; j0 += 4) {
        float4 s = make_float4(p[j0], p[j0 + 1], p[j0 + 2], p[j0 + 3]);
        *reinterpret_cast<float4*>(o + j0) = s;
    }
    const float4* nf4 = reinterpret_cast<const float4*>(nfeat + (size_t)n * E);
    #pragma unroll
    for (int j0 = 0; j0 < E; j0 += 4) {
        float4 v = nf4[j0 / 4];
        p[j0] += v.x; p[j0 + 1] += v.y; p[j0 + 2] += v.z; p[j0 + 3] += v.w;
    }
    float a[E];
    #pragma unroll
    for (int j = 0; j < E; j++) a[j] = 0.f;
    #pragma unroll
    for (int c = 0; c < E; c++) {
        float v = p[c];
        const float* w = aW1 + (size_t)(E + c) * E;
        #pragma unroll
        for (int j = 0; j < E; j++) a[j] = fmaf(v, w[j], a[j]);
    }
    store_bf16_row64(qatt + (size_t)n * E, a);
}

// ---- attention: MFMA for h2 GEMM. One wave owns 8 nodes = 192 h1-rows = 12 M-tiles.
// A-frag (16x16x32): lane l -> row = l&15, k = 8*(l>>4)+e  (built in-register from gathers)
// B-frag:            lane l -> col = l&15, k = 8*(l>>4)+e  (aW2, loaded once per wave)
// C/D (m89-verified): col = lane&15, row = (lane>>4)*4 + reg
__global__ __launch_bounds__(256) void k_att(const int* __restrict__ nodes,
                                             const int* __restrict__ nidx,
                                             const __hip_bfloat16* __restrict__ iproj,
                                             const __hip_bfloat16* __restrict__ iatt,
                                             const __hip_bfloat16* __restrict__ qatt,
                                             const float* __restrict__ aW2,
                                             const float* __restrict__ ab2,
                                             const float* __restrict__ aW3,
                                             const int* __restrict__ winner,
                                             float* __restrict__ outE) {
    __shared__ float s_scores[4][192];
    const int wave = threadIdx.x >> 6, lane = threadIdx.x & 63;
    const int lo = lane & 15, hi = lane >> 4;
    const int n0 = (blockIdx.x * 4 + wave) * 8;   // grid = N_NODES/32 exactly

    // B fragments: B[s][u] holds aW2[k=32s+8hi+e][col=16u+lo]
    bf16x8 B[2][4];
    #pragma unroll
    for (int s = 0; s < 2; s++) {
        #pragma unroll
        for (int u = 0; u < 4; u++) {
            bf16x8 b;
            #pragma unroll
            for (int e = 0; e < 8; e++) {
                int kk = 32 * s + 8 * hi + e;
                b[e] = f2bf(aW2[(size_t)kk * E + 16 * u + lo]);
            }
            B[s][u] = b;
        }
    }
    float b2c[4], w3c[4];
    #pragma unroll
    for (int u = 0; u < 4; u++) { b2c[u] = ab2[16 * u + lo]; w3c[u] = aW3[16 * u + lo]; }

    // prefetch neighbor ids for all 12 tiles (breaks idx->gather chain)
    int idxs[12], nls[12];
    #pragma unroll
    for (int t = 0; t < 12; t++) {
        int r = t * 16 + lo;             // this lane's h1 row within the wave (0..191)
        int nl = r / 24;
        nls[t] = nl;
        idxs[t] = nidx[(size_t)(n0 + nl) * KNEI + (r - nl * 24)];
    }

    #pragma unroll
    for (int t = 0; t < 12; t++) {
        const bf16x8* iarow = reinterpret_cast<const bf16x8*>(iatt + (size_t)idxs[t] * E);
        const bf16x8* qrow  = reinterpret_cast<const bf16x8*>(qatt + (size_t)(n0 + nls[t]) * E);
        f32x4 acc[4];
        #pragma unroll
        for (int u = 0; u < 4; u++) acc[u] = (f32x4){0.f, 0.f, 0.f, 0.f};
        #pragma unroll
        for (int s = 0; s < 2; s++) {
            bf16x8 ia = iarow[4 * s + hi];
            bf16x8 qa = qrow[4 * s + hi];
            bf16x8 a;
            #pragma unroll
            for (int e = 0; e < 8; e++) {
                float v = bf2f(ia[e]) + bf2f(qa[e]);
                a[e] = f2bf(fmaxf(v, 0.f));
            }
            #pragma unroll
            for (int u = 0; u < 4; u++)
                acc[u] = __builtin_amdgcn_mfma_f32_16x16x32_bf16(a, B[s][u], acc[u], 0, 0, 0);
        }
        // score partial: relu(h2 + ab2) . aW3 over this lane's 16-col slice
        f32x4 sum;
        #pragma unroll
        for (int reg = 0; reg < 4; reg++) {
            float v = 0.f;
            #pragma unroll
            for (int u = 0; u < 4; u++)
                v += fmaxf(acc[u][reg] + b2c[u], 0.f) * w3c[u];
            sum[reg] = v;
        }
        #pragma unroll
        for (int m = 1; m < 16; m <<= 1) {
            #pragma unroll
            for (int reg = 0; reg < 4; reg++)
                sum[reg] += __shfl_xor(sum[reg], m);
        }
        if (lo == 0)
            *reinterpret_cast<f32x4*>(&s_scores[wave][t * 16 + hi * 4]) = sum;
    }
    __syncthreads();

    // softmax over 24 neighbors + weighted i_proj aggregation, per node
    #pragma unroll 1
    for (int nd = 0; nd < 8; nd++) {
        int n = n0 + nd;
        int k5 = lane & 31;
        bool kv = k5 < KNEI;
        float sc = kv ? s_scores[wave][nd * KNEI + k5] : -1e30f;
        float mx = sc;
        #pragma unroll
        for (int m = 1; m < 32; m <<= 1) mx = fmaxf(mx, __shfl_xor(mx, m));
        float e = kv ? __expf(sc - mx) : 0.f;
        float ssum = e;
        #pragma unroll
        for (int m = 1; m < 32; m <<= 1) ssum += __shfl_xor(ssum, m);
        float w = e / ssum;
        int idxv = kv ? nidx[(size_t)n * KNEI + k5] : 0;

        float emb = 0.f;
        const short* ip = reinterpret_cast<const short*>(iproj);
        #pragma unroll
        for (int k = 0; k < KNEI; k++) {
            int sidx = __builtin_amdgcn_readlane(idxv, k);
            float wk = rdlane_f(w, k);
            emb = fmaf(wk, bf2f(ip[(size_t)sidx * E + lane]), emb);
        }
        int un = nodes[n];
        if (winner[un] == n) outE[(size_t)un * E + lane] = emb;
    }
}

extern "C" void kernel_launch(void* const* d_in, const int* in_sizes, int n_in,
                              void* d_out, int out_size, void* d_ws, size_t ws_size,
                              hipStream_t stream) {
    const int*   nodes = (const int*)d_in[0];
    const float* nfeat = (const float*)d_in[1];
    const int*   nidx  = (const int*)d_in[2];
    const float* uwt   = (const float*)d_in[3];
    const float* iwt   = (const float*)d_in[4];
    const float* uW    = (const float*)d_in[5];
    const float* ub    = (const float*)d_in[6];
    const float* iW    = (const float*)d_in[7];
    const float* ib    = (const float*)d_in[8];
    const float* aW1   = (const float*)d_in[9];
    const float* ab1   = (const float*)d_in[10];
    const float* aW2   = (const float*)d_in[11];
    const float* ab2   = (const float*)d_in[12];
    const float* aW3   = (const float*)d_in[13];
    // d_in[14] = ab3: softmax-shift-invariant, unused

    float* out_nf  = (float*)d_out;
    float* out_emb = out_nf + (size_t)N_NODES * E;

    char* ws = (char*)d_ws;
    __hip_bfloat16* iproj = (__hip_bfloat16*)(ws);
    __hip_bfloat16* iatt  = (__hip_bfloat16*)(ws + 25600000);
    __hip_bfloat16* qatt  = (__hip_bfloat16*)(ws + 51200000);
    int*            winner = (int*)(ws + 64000000);

    hipMemsetAsync(winner, 0xFF, (size_t)N_USERS * sizeof(int), stream);
    hipMemsetAsync(out_emb, 0, (size_t)N_USERS * E * sizeof(float), stream);

    k_winner<<<(N_NODES + 255) / 256, 256, 0, stream>>>(nodes, winner);
    k_item<<<(N_ITEMS + 255) / 256, 256, 0, stream>>>(iwt, iW, ib, aW1, ab1, iproj, iatt);
    k_node<<<(N_NODES + 255) / 256, 256, 0, stream>>>(nodes, nfeat, uwt, uW, ub, aW1,
                                                      out_nf, qatt);
    k_att<<<N_NODES / 32, 256, 0, stream>>>(nodes, nidx, iproj, iatt, qatt,
                                            aW2, ab2, aW3, winner, out_emb);
}

// Round 3
// 236.770 us; speedup vs baseline: 4.1622x; 2.2128x over previous
//
#include <hip/hip_runtime.h>
#include <hip/hip_bf16.h>

#define N_NODES 100000
#define N_USERS 200000
#define N_ITEMS 200000
#define KNEI 24
#define E 64
#define F 128

typedef __attribute__((ext_vector_type(8))) short bf16x8;
typedef __attribute__((ext_vector_type(4))) float f32x4;

// ---- workspace layout (bytes) ----
// i_proj bf16 [N_ITEMS][64] : off 0          size 25,600,000
// i_att  bf16 [N_ITEMS][64] : off 25,600,000 size 25,600,000
// q_att  bf16 [N_NODES][64] : off 51,200,000 size 12,800,000
// winner int  [N_USERS]     : off 64,000,000 size    800,000
// W'     f32  [128][64]     : off 64,800,000 size     32,768
// b'     f32  [64]          : off 64,832,768 size        256

__device__ inline float bf2f(short s) {
    unsigned u = ((unsigned)(unsigned short)s) << 16;
    return __uint_as_float(u);
}
__device__ inline short f2bf(float f) {
    __hip_bfloat16 h = __float2bfloat16(f);
    return *reinterpret_cast<short*>(&h);
}
__device__ inline float rdlane_f(float v, int l) {
    return __uint_as_float(__builtin_amdgcn_readlane(__float_as_uint(v), l));
}
__device__ inline bf16x8 pack8(float4 a, float4 b) {
    bf16x8 r;
    r[0] = f2bf(a.x); r[1] = f2bf(a.y); r[2] = f2bf(a.z); r[3] = f2bf(a.w);
    r[4] = f2bf(b.x); r[5] = f2bf(b.y); r[6] = f2bf(b.z); r[7] = f2bf(b.w);
    return r;
}

// ---- fused attention weights: W' = iW @ aW1[:64] ; b' = ib@aW1[:64] + ab1 ----
__global__ __launch_bounds__(256) void k_fuse(const float* __restrict__ iW,
                                              const float* __restrict__ aW1,
                                              const float* __restrict__ ib,
                                              const float* __restrict__ ab1,
                                              float* __restrict__ Wp,
                                              float* __restrict__ bp) {
    int g = blockIdx.x * 256 + threadIdx.x;      // 0..8191
    int f = g >> 6, c = g & 63;
    float s = 0.f;
    for (int j = 0; j < 64; j++) s = fmaf(iW[f * 64 + j], aW1[j * 64 + c], s);
    Wp[g] = s;
    if (g < 64) {
        float b = ab1[g];
        for (int j = 0; j < 64; j++) b = fmaf(ib[j], aW1[j * 64 + g], b);
        bp[g] = b;
    }
}

// MFMA lane mappings (correctness-proven by round-2 k_att):
//   A frag 16x16x32: lane l -> row = l&15, k = 8*(l>>4)+e
//   B frag:          lane l -> col = l&15, k = 8*(l>>4)+e
//   C/D:             lane l -> col = l&15, row = 4*(l>>4)+reg

// ---- per-item: i_proj = row@iW + ib ; i_att = row@W' + b' (one A pass) ----
__global__ __launch_bounds__(256, 2) void k_item(const float* __restrict__ iwt,
                                                 const float* __restrict__ iW,
                                                 const float* __restrict__ ib,
                                                 const float* __restrict__ Wp,
                                                 const float* __restrict__ bp,
                                                 __hip_bfloat16* __restrict__ iproj,
                                                 __hip_bfloat16* __restrict__ iatt) {
    const int wave = threadIdx.x >> 6, lane = threadIdx.x & 63;
    const int lo = lane & 15, hi = lane >> 4;

    bf16x8 B1[4][4], B2[4][4];
    #pragma unroll
    for (int s = 0; s < 4; s++) {
        #pragma unroll
        for (int u = 0; u < 4; u++) {
            bf16x8 b1, b2;
            #pragma unroll
            for (int e = 0; e < 8; e++) {
                int k = 32 * s + 8 * hi + e;
                b1[e] = f2bf(iW[k * 64 + 16 * u + lo]);
                b2[e] = f2bf(Wp[k * 64 + 16 * u + lo]);
            }
            B1[s][u] = b1; B2[s][u] = b2;
        }
    }
    float bi[4], ba[4];
    #pragma unroll
    for (int u = 0; u < 4; u++) { bi[u] = ib[16 * u + lo]; ba[u] = bp[16 * u + lo]; }

    const int wid = blockIdx.x * 4 + wave;
    for (int t = wid; t < N_ITEMS / 16; t += 512 * 4) {
        int r0 = t * 16;
        const float4* Ap = reinterpret_cast<const float4*>(iwt + (size_t)(r0 + lo) * F);
        bf16x8 A[4];
        #pragma unroll
        for (int s = 0; s < 4; s++)
            A[s] = pack8(Ap[8 * s + 2 * hi], Ap[8 * s + 2 * hi + 1]);
        f32x4 acc1[4], acc2[4];
        #pragma unroll
        for (int u = 0; u < 4; u++) {
            acc1[u] = (f32x4){0.f, 0.f, 0.f, 0.f};
            acc2[u] = (f32x4){0.f, 0.f, 0.f, 0.f};
        }
        #pragma unroll
        for (int s = 0; s < 4; s++) {
            #pragma unroll
            for (int u = 0; u < 4; u++) {
                acc1[u] = __builtin_amdgcn_mfma_f32_16x16x32_bf16(A[s], B1[s][u], acc1[u], 0, 0, 0);
                acc2[u] = __builtin_amdgcn_mfma_f32_16x16x32_bf16(A[s], B2[s][u], acc2[u], 0, 0, 0);
            }
        }
        #pragma unroll
        for (int u = 0; u < 4; u++) {
            #pragma unroll
            for (int reg = 0; reg < 4; reg++) {
                size_t off = (size_t)(r0 + 4 * hi + reg) * E + 16 * u + lo;
                iproj[off] = __float2bfloat16(acc1[u][reg] + bi[u]);
                iatt[off]  = __float2bfloat16(acc2[u][reg] + ba[u]);
            }
        }
    }
}

// ---- per-node pass 1: nodes_fea = u_weight[nodes]@uW + ub (f32 out) + winner ----
__global__ __launch_bounds__(256, 2) void k_node1(const int* __restrict__ nodes,
                                                  const float* __restrict__ uwt,
                                                  const float* __restrict__ uW,
                                                  const float* __restrict__ ub,
                                                  float* __restrict__ out_nf,
                                                  int* __restrict__ winner) {
    const int wave = threadIdx.x >> 6, lane = threadIdx.x & 63;
    const int lo = lane & 15, hi = lane >> 4;

    bf16x8 B[4][4];
    #pragma unroll
    for (int s = 0; s < 4; s++) {
        #pragma unroll
        for (int u = 0; u < 4; u++) {
            bf16x8 b;
            #pragma unroll
            for (int e = 0; e < 8; e++) {
                int k = 32 * s + 8 * hi + e;
                b[e] = f2bf(uW[k * 64 + 16 * u + lo]);
            }
            B[s][u] = b;
        }
    }
    float bu[4];
    #pragma unroll
    for (int u = 0; u < 4; u++) bu[u] = ub[16 * u + lo];

    const int wid = blockIdx.x * 4 + wave;
    for (int t = wid; t < N_NODES / 16; t += 256 * 4) {
        int r0 = t * 16;
        int n = r0 + lo;
        int un = nodes[n];
        if (hi == 0) atomicMax(&winner[un], n);
        const float4* Ap = reinterpret_cast<const float4*>(uwt + (size_t)un * F);
        bf16x8 A[4];
        #pragma unroll
        for (int s = 0; s < 4; s++)
            A[s] = pack8(Ap[8 * s + 2 * hi], Ap[8 * s + 2 * hi + 1]);
        f32x4 acc[4];
        #pragma unroll
        for (int u = 0; u < 4; u++) acc[u] = (f32x4){0.f, 0.f, 0.f, 0.f};
        #pragma unroll
        for (int s = 0; s < 4; s++) {
            #pragma unroll
            for (int u = 0; u < 4; u++)
                acc[u] = __builtin_amdgcn_mfma_f32_16x16x32_bf16(A[s], B[s][u], acc[u], 0, 0, 0);
        }
        #pragma unroll
        for (int u = 0; u < 4; u++) {
            #pragma unroll
            for (int reg = 0; reg < 4; reg++)
                out_nf[(size_t)(r0 + 4 * hi + reg) * E + 16 * u + lo] = acc[u][reg] + bu[u];
        }
    }
}

// ---- per-node pass 2: q_att = (nodes_fea + n_feature) @ aW1[64:] (bf16 ws) ----
__global__ __launch_bounds__(256, 2) void k_node2(const float* __restrict__ out_nf,
                                                  const float* __restrict__ nfeat,
                                                  const float* __restrict__ aW1,
                                                  __hip_bfloat16* __restrict__ qatt) {
    const int wave = threadIdx.x >> 6, lane = threadIdx.x & 63;
    const int lo = lane & 15, hi = lane >> 4;

    bf16x8 B[2][4];
    #pragma unroll
    for (int s = 0; s < 2; s++) {
        #pragma unroll
        for (int u = 0; u < 4; u++) {
            bf16x8 b;
            #pragma unroll
            for (int e = 0; e < 8; e++) {
                int k = 32 * s + 8 * hi + e;
                b[e] = f2bf(aW1[(size_t)(E + k) * 64 + 16 * u + lo]);
            }
            B[s][u] = b;
        }
    }

    const int wid = blockIdx.x * 4 + wave;
    for (int t = wid; t < N_NODES / 16; t += 256 * 4) {
        int r0 = t * 16;
        const float4* Op = reinterpret_cast<const float4*>(out_nf + (size_t)(r0 + lo) * E);
        const float4* Np = reinterpret_cast<const float4*>(nfeat + (size_t)(r0 + lo) * E);
        bf16x8 A[2];
        #pragma unroll
        for (int s = 0; s < 2; s++) {
            float4 o0 = Op[8 * s + 2 * hi], o1 = Op[8 * s + 2 * hi + 1];
            float4 n0 = Np[8 * s + 2 * hi], n1 = Np[8 * s + 2 * hi + 1];
            float4 q0 = make_float4(o0.x + n0.x, o0.y + n0.y, o0.z + n0.z, o0.w + n0.w);
            float4 q1 = make_float4(o1.x + n1.x, o1.y + n1.y, o1.z + n1.z, o1.w + n1.w);
            A[s] = pack8(q0, q1);
        }
        f32x4 acc[4];
        #pragma unroll
        for (int u = 0; u < 4; u++) acc[u] = (f32x4){0.f, 0.f, 0.f, 0.f};
        #pragma unroll
        for (int s = 0; s < 2; s++) {
            #pragma unroll
            for (int u = 0; u < 4; u++)
                acc[u] = __builtin_amdgcn_mfma_f32_16x16x32_bf16(A[s], B[s][u], acc[u], 0, 0, 0);
        }
        #pragma unroll
        for (int u = 0; u < 4; u++) {
            #pragma unroll
            for (int reg = 0; reg < 4; reg++)
                qatt[(size_t)(r0 + 4 * hi + reg) * E + 16 * u + lo] =
                    __float2bfloat16(acc[u][reg]);
        }
    }
}

// ---- attention: MFMA h2 GEMM, one wave owns 8 nodes = 12 M-tiles (unchanged) ----
__global__ __launch_bounds__(256) void k_att(const int* __restrict__ nodes,
                                             const int* __restrict__ nidx,
                                             const __hip_bfloat16* __restrict__ iproj,
                                             const __hip_bfloat16* __restrict__ iatt,
                                             const __hip_bfloat16* __restrict__ qatt,
                                             const float* __restrict__ aW2,
                                             const float* __restrict__ ab2,
                                             const float* __restrict__ aW3,
                                             const int* __restrict__ winner,
                                             float* __restrict__ outE) {
    __shared__ float s_scores[4][192];
    const int wave = threadIdx.x >> 6, lane = threadIdx.x & 63;
    const int lo = lane & 15, hi = lane >> 4;
    const int n0 = (blockIdx.x * 4 + wave) * 8;   // grid = N_NODES/32 exactly

    bf16x8 B[2][4];
    #pragma unroll
    for (int s = 0; s < 2; s++) {
        #pragma unroll
        for (int u = 0; u < 4; u++) {
            bf16x8 b;
            #pragma unroll
            for (int e = 0; e < 8; e++) {
                int kk = 32 * s + 8 * hi + e;
                b[e] = f2bf(aW2[(size_t)kk * E + 16 * u + lo]);
            }
            B[s][u] = b;
        }
    }
    float b2c[4], w3c[4];
    #pragma unroll
    for (int u = 0; u < 4; u++) { b2c[u] = ab2[16 * u + lo]; w3c[u] = aW3[16 * u + lo]; }

    int idxs[12], nls[12];
    #pragma unroll
    for (int t = 0; t < 12; t++) {
        int r = t * 16 + lo;
        int nl = r / 24;
        nls[t] = nl;
        idxs[t] = nidx[(size_t)(n0 + nl) * KNEI + (r - nl * 24)];
    }

    #pragma unroll
    for (int t = 0; t < 12; t++) {
        const bf16x8* iarow = reinterpret_cast<const bf16x8*>(iatt + (size_t)idxs[t] * E);
        const bf16x8* qrow  = reinterpret_cast<const bf16x8*>(qatt + (size_t)(n0 + nls[t]) * E);
        f32x4 acc[4];
        #pragma unroll
        for (int u = 0; u < 4; u++) acc[u] = (f32x4){0.f, 0.f, 0.f, 0.f};
        #pragma unroll
        for (int s = 0; s < 2; s++) {
            bf16x8 ia = iarow[4 * s + hi];
            bf16x8 qa = qrow[4 * s + hi];
            bf16x8 a;
            #pragma unroll
            for (int e = 0; e < 8; e++) {
                float v = bf2f(ia[e]) + bf2f(qa[e]);
                a[e] = f2bf(fmaxf(v, 0.f));
            }
            #pragma unroll
            for (int u = 0; u < 4; u++)
                acc[u] = __builtin_amdgcn_mfma_f32_16x16x32_bf16(a, B[s][u], acc[u], 0, 0, 0);
        }
        f32x4 sum;
        #pragma unroll
        for (int reg = 0; reg < 4; reg++) {
            float v = 0.f;
            #pragma unroll
            for (int u = 0; u < 4; u++)
                v += fmaxf(acc[u][reg] + b2c[u], 0.f) * w3c[u];
            sum[reg] = v;
        }
        #pragma unroll
        for (int m = 1; m < 16; m <<= 1) {
            #pragma unroll
            for (int reg = 0; reg < 4; reg++)
                sum[reg] += __shfl_xor(sum[reg], m);
        }
        if (lo == 0)
            *reinterpret_cast<f32x4*>(&s_scores[wave][t * 16 + hi * 4]) = sum;
    }
    __syncthreads();

    #pragma unroll 1
    for (int nd = 0; nd < 8; nd++) {
        int n = n0 + nd;
        int k5 = lane & 31;
        bool kv = k5 < KNEI;
        float sc = kv ? s_scores[wave][nd * KNEI + k5] : -1e30f;
        float mx = sc;
        #pragma unroll
        for (int m = 1; m < 32; m <<= 1) mx = fmaxf(mx, __shfl_xor(mx, m));
        float e = kv ? __expf(sc - mx) : 0.f;
        float ssum = e;
        #pragma unroll
        for (int m = 1; m < 32; m <<= 1) ssum += __shfl_xor(ssum, m);
        float w = e / ssum;
        int idxv = kv ? nidx[(size_t)n * KNEI + k5] : 0;

        float emb = 0.f;
        const short* ip = reinterpret_cast<const short*>(iproj);
        #pragma unroll
        for (int k = 0; k < KNEI; k++) {
            int sidx = __builtin_amdgcn_readlane(idxv, k);
            float wk = rdlane_f(w, k);
            emb = fmaf(wk, bf2f(ip[(size_t)sidx * E + lane]), emb);
        }
        int un = nodes[n];
        if (winner[un] == n) outE[(size_t)un * E + lane] = emb;
    }
}

extern "C" void kernel_launch(void* const* d_in, const int* in_sizes, int n_in,
                              void* d_out, int out_size, void* d_ws, size_t ws_size,
                              hipStream_t stream) {
    const int*   nodes = (const int*)d_in[0];
    const float* nfeat = (const float*)d_in[1];
    const int*   nidx  = (const int*)d_in[2];
    const float* uwt   = (const float*)d_in[3];
    const float* iwt   = (const float*)d_in[4];
    const float* uW    = (const float*)d_in[5];
    const float* ub    = (const float*)d_in[6];
    const float* iW    = (const float*)d_in[7];
    const float* ib    = (const float*)d_in[8];
    const float* aW1   = (const float*)d_in[9];
    const float* ab1   = (const float*)d_in[10];
    const float* aW2   = (const float*)d_in[11];
    const float* ab2   = (const float*)d_in[12];
    const float* aW3   = (const float*)d_in[13];
    // d_in[14] = ab3: softmax-shift-invariant, unused

    float* out_nf  = (float*)d_out;
    float* out_emb = out_nf + (size_t)N_NODES * E;

    char* ws = (char*)d_ws;
    __hip_bfloat16* iproj = (__hip_bfloat16*)(ws);
    __hip_bfloat16* iatt  = (__hip_bfloat16*)(ws + 25600000);
    __hip_bfloat16* qatt  = (__hip_bfloat16*)(ws + 51200000);
    int*            winner = (int*)(ws + 64000000);
    float*          Wp     = (float*)(ws + 64800000);
    float*          bp     = (float*)(ws + 64832768);

    hipMemsetAsync(winner, 0xFF, (size_t)N_USERS * sizeof(int), stream);
    hipMemsetAsync(out_emb, 0, (size_t)N_USERS * E * sizeof(float), stream);

    k_fuse<<<32, 256, 0, stream>>>(iW, aW1, ib, ab1, Wp, bp);
    k_item<<<512, 256, 0, stream>>>(iwt, iW, ib, Wp, bp, iproj, iatt);
    k_node1<<<256, 256, 0, stream>>>(nodes, uwt, uW, ub, out_nf, winner);
    k_node2<<<256, 256, 0, stream>>>(out_nf, nfeat, aW1, qatt);
    k_att<<<N_NODES / 32, 256, 0, stream>>>(nodes, nidx, iproj, iatt, qatt,
                                            aW2, ab2, aW3, winner, out_emb);
}

// Round 4
// 208.080 us; speedup vs baseline: 4.7361x; 1.1379x over previous
//
#include <hip/hip_runtime.h>
#include <hip/hip_bf16.h>

#define N_NODES 100000
#define N_USERS 200000
#define N_ITEMS 200000
#define KNEI 24
#define E 64
#define F 128

typedef __attribute__((ext_vector_type(8))) short bf16x8;
typedef __attribute__((ext_vector_type(4))) float f32x4;

// ---- workspace layout (bytes) ----
// i_proj bf16 [N_ITEMS][64] : off 0          size 25,600,000
// i_att  bf16 [N_ITEMS][64] : off 25,600,000 size 25,600,000
// q_att  bf16 [N_NODES][64] : off 51,200,000 size 12,800,000
// winner int  [N_USERS]     : off 64,000,000 size    800,000
// W'     f32  [128][64]     : off 64,800,000 size     32,768
// b'     f32  [64]          : off 64,832,768 size        256
// B2img  bf16 [8][64][8]    : off 64,833,024 size      8,192   (aW2 frags, reg-image)
// bw     f32  [64][8]       : off 64,841,216 size      2,048   (ab2|aW3 lane-image)

__device__ inline float bf2f(short s) {
    unsigned u = ((unsigned)(unsigned short)s) << 16;
    return __uint_as_float(u);
}
__device__ inline short f2bf(float f) {
    __hip_bfloat16 h = __float2bfloat16(f);
    return *reinterpret_cast<short*>(&h);
}
__device__ inline bf16x8 pack8(float4 a, float4 b) {
    bf16x8 r;
    r[0] = f2bf(a.x); r[1] = f2bf(a.y); r[2] = f2bf(a.z); r[3] = f2bf(a.w);
    r[4] = f2bf(b.x); r[5] = f2bf(b.y); r[6] = f2bf(b.z); r[7] = f2bf(b.w);
    return r;
}

// ---- fuse: W' = iW@aW1a ; b' = ib@aW1a + ab1 ; pack aW2 frag image + bias image ----
__global__ __launch_bounds__(256) void k_fuse(const float* __restrict__ iW,
                                              const float* __restrict__ aW1,
                                              const float* __restrict__ ib,
                                              const float* __restrict__ ab1,
                                              const float* __restrict__ aW2,
                                              const float* __restrict__ ab2,
                                              const float* __restrict__ aW3,
                                              float* __restrict__ Wp,
                                              float* __restrict__ bp,
                                              bf16x8* __restrict__ B2img,
                                              float* __restrict__ bw) {
    int g = blockIdx.x * 256 + threadIdx.x;
    if (g < 8192) {
        int f = g >> 6, c = g & 63;
        float s = 0.f;
        for (int j = 0; j < 64; j++) s = fmaf(iW[f * 64 + j], aW1[j * 64 + c], s);
        Wp[g] = s;
        if (g < 64) {
            float b = ab1[g];
            for (int j = 0; j < 64; j++) b = fmaf(ib[j], aW1[j * 64 + g], b);
            bp[g] = b;
        }
    } else if (g < 8192 + 512) {
        int h = g - 8192;
        int f = h >> 6, l = h & 63;
        int s = f >> 2, u = f & 3;
        int lo = l & 15, hi = l >> 4;
        bf16x8 b;
        #pragma unroll
        for (int e = 0; e < 8; e++)
            b[e] = f2bf(aW2[(size_t)(32 * s + 8 * hi + e) * 64 + 16 * u + lo]);
        B2img[h] = b;
        if (f == 0) {
            #pragma unroll
            for (int uu = 0; uu < 4; uu++) {
                bw[l * 8 + uu]     = ab2[16 * uu + lo];
                bw[l * 8 + 4 + uu] = aW3[16 * uu + lo];
            }
        }
    }
}

// MFMA lane mappings (correctness-proven rounds 2-3):
//   A frag 16x16x32: lane l -> row = l&15, k = 8*(l>>4)+e
//   B frag:          lane l -> col = l&15, k = 8*(l>>4)+e
//   C/D:             lane l -> col = l&15, row = 4*(l>>4)+reg

// ---- per-item: i_proj = row@iW + ib ; i_att = row@W' + b' (one A pass) ----
__global__ __launch_bounds__(256, 2) void k_item(const float* __restrict__ iwt,
                                                 const float* __restrict__ iW,
                                                 const float* __restrict__ ib,
                                                 const float* __restrict__ Wp,
                                                 const float* __restrict__ bp,
                                                 __hip_bfloat16* __restrict__ iproj,
                                                 __hip_bfloat16* __restrict__ iatt) {
    const int wave = threadIdx.x >> 6, lane = threadIdx.x & 63;
    const int lo = lane & 15, hi = lane >> 4;

    bf16x8 B1[4][4], B2[4][4];
    #pragma unroll
    for (int s = 0; s < 4; s++) {
        #pragma unroll
        for (int u = 0; u < 4; u++) {
            bf16x8 b1, b2;
            #pragma unroll
            for (int e = 0; e < 8; e++) {
                int k = 32 * s + 8 * hi + e;
                b1[e] = f2bf(iW[k * 64 + 16 * u + lo]);
                b2[e] = f2bf(Wp[k * 64 + 16 * u + lo]);
            }
            B1[s][u] = b1; B2[s][u] = b2;
        }
    }
    float bi[4], ba[4];
    #pragma unroll
    for (int u = 0; u < 4; u++) { bi[u] = ib[16 * u + lo]; ba[u] = bp[16 * u + lo]; }

    const int wid = blockIdx.x * 4 + wave;
    for (int t = wid; t < N_ITEMS / 16; t += 512 * 4) {
        int r0 = t * 16;
        const float4* Ap = reinterpret_cast<const float4*>(iwt + (size_t)(r0 + lo) * F);
        bf16x8 A[4];
        #pragma unroll
        for (int s = 0; s < 4; s++)
            A[s] = pack8(Ap[8 * s + 2 * hi], Ap[8 * s + 2 * hi + 1]);
        f32x4 acc1[4], acc2[4];
        #pragma unroll
        for (int u = 0; u < 4; u++) {
            acc1[u] = (f32x4){0.f, 0.f, 0.f, 0.f};
            acc2[u] = (f32x4){0.f, 0.f, 0.f, 0.f};
        }
        #pragma unroll
        for (int s = 0; s < 4; s++) {
            #pragma unroll
            for (int u = 0; u < 4; u++) {
                acc1[u] = __builtin_amdgcn_mfma_f32_16x16x32_bf16(A[s], B1[s][u], acc1[u], 0, 0, 0);
                acc2[u] = __builtin_amdgcn_mfma_f32_16x16x32_bf16(A[s], B2[s][u], acc2[u], 0, 0, 0);
            }
        }
        #pragma unroll
        for (int u = 0; u < 4; u++) {
            #pragma unroll
            for (int reg = 0; reg < 4; reg++) {
                size_t off = (size_t)(r0 + 4 * hi + reg) * E + 16 * u + lo;
                iproj[off] = __float2bfloat16(acc1[u][reg] + bi[u]);
                iatt[off]  = __float2bfloat16(acc2[u][reg] + ba[u]);
            }
        }
    }
}

// ---- per-node pass 1: nodes_fea = u_weight[nodes]@uW + ub (f32 out) + winner ----
__global__ __launch_bounds__(256, 2) void k_node1(const int* __restrict__ nodes,
                                                  const float* __restrict__ uwt,
                                                  const float* __restrict__ uW,
                                                  const float* __restrict__ ub,
                                                  float* __restrict__ out_nf,
                                                  int* __restrict__ winner) {
    const int wave = threadIdx.x >> 6, lane = threadIdx.x & 63;
    const int lo = lane & 15, hi = lane >> 4;

    bf16x8 B[4][4];
    #pragma unroll
    for (int s = 0; s < 4; s++) {
        #pragma unroll
        for (int u = 0; u < 4; u++) {
            bf16x8 b;
            #pragma unroll
            for (int e = 0; e < 8; e++) {
                int k = 32 * s + 8 * hi + e;
                b[e] = f2bf(uW[k * 64 + 16 * u + lo]);
            }
            B[s][u] = b;
        }
    }
    float bu[4];
    #pragma unroll
    for (int u = 0; u < 4; u++) bu[u] = ub[16 * u + lo];

    const int wid = blockIdx.x * 4 + wave;
    for (int t = wid; t < N_NODES / 16; t += 256 * 4) {
        int r0 = t * 16;
        int n = r0 + lo;
        int un = nodes[n];
        if (hi == 0) atomicMax(&winner[un], n);
        const float4* Ap = reinterpret_cast<const float4*>(uwt + (size_t)un * F);
        bf16x8 A[4];
        #pragma unroll
        for (int s = 0; s < 4; s++)
            A[s] = pack8(Ap[8 * s + 2 * hi], Ap[8 * s + 2 * hi + 1]);
        f32x4 acc[4];
        #pragma unroll
        for (int u = 0; u < 4; u++) acc[u] = (f32x4){0.f, 0.f, 0.f, 0.f};
        #pragma unroll
        for (int s = 0; s < 4; s++) {
            #pragma unroll
            for (int u = 0; u < 4; u++)
                acc[u] = __builtin_amdgcn_mfma_f32_16x16x32_bf16(A[s], B[s][u], acc[u], 0, 0, 0);
        }
        #pragma unroll
        for (int u = 0; u < 4; u++) {
            #pragma unroll
            for (int reg = 0; reg < 4; reg++)
                out_nf[(size_t)(r0 + 4 * hi + reg) * E + 16 * u + lo] = acc[u][reg] + bu[u];
        }
    }
}

// ---- per-node pass 2: q_att = (nodes_fea + n_feature) @ aW1[64:] (bf16 ws) ----
__global__ __launch_bounds__(256, 2) void k_node2(const float* __restrict__ out_nf,
                                                  const float* __restrict__ nfeat,
                                                  const float* __restrict__ aW1,
                                                  __hip_bfloat16* __restrict__ qatt) {
    const int wave = threadIdx.x >> 6, lane = threadIdx.x & 63;
    const int lo = lane & 15, hi = lane >> 4;

    bf16x8 B[2][4];
    #pragma unroll
    for (int s = 0; s < 2; s++) {
        #pragma unroll
        for (int u = 0; u < 4; u++) {
            bf16x8 b;
            #pragma unroll
            for (int e = 0; e < 8; e++) {
                int k = 32 * s + 8 * hi + e;
                b[e] = f2bf(aW1[(size_t)(E + k) * 64 + 16 * u + lo]);
            }
            B[s][u] = b;
        }
    }

    const int wid = blockIdx.x * 4 + wave;
    for (int t = wid; t < N_NODES / 16; t += 256 * 4) {
        int r0 = t * 16;
        const float4* Op = reinterpret_cast<const float4*>(out_nf + (size_t)(r0 + lo) * E);
        const float4* Np = reinterpret_cast<const float4*>(nfeat + (size_t)(r0 + lo) * E);
        bf16x8 A[2];
        #pragma unroll
        for (int s = 0; s < 2; s++) {
            float4 o0 = Op[8 * s + 2 * hi], o1 = Op[8 * s + 2 * hi + 1];
            float4 n0 = Np[8 * s + 2 * hi], n1 = Np[8 * s + 2 * hi + 1];
            float4 q0 = make_float4(o0.x + n0.x, o0.y + n0.y, o0.z + n0.z, o0.w + n0.w);
            float4 q1 = make_float4(o1.x + n1.x, o1.y + n1.y, o1.z + n1.z, o1.w + n1.w);
            A[s] = pack8(q0, q1);
        }
        f32x4 acc[4];
        #pragma unroll
        for (int u = 0; u < 4; u++) acc[u] = (f32x4){0.f, 0.f, 0.f, 0.f};
        #pragma unroll
        for (int s = 0; s < 2; s++) {
            #pragma unroll
            for (int u = 0; u < 4; u++)
                acc[u] = __builtin_amdgcn_mfma_f32_16x16x32_bf16(A[s], B[s][u], acc[u], 0, 0, 0);
        }
        #pragma unroll
        for (int u = 0; u < 4; u++) {
            #pragma unroll
            for (int reg = 0; reg < 4; reg++)
                qatt[(size_t)(r0 + 4 * hi + reg) * E + 16 * u + lo] =
                    __float2bfloat16(acc[u][reg]);
        }
    }
}

// ---- attention: MFMA h2 GEMM + parallel softmax/agg. Wave owns 8 nodes = 12 M-tiles.
__global__ __launch_bounds__(256) void k_att(const int* __restrict__ nodes,
                                             const int* __restrict__ nidx,
                                             const __hip_bfloat16* __restrict__ iproj,
                                             const __hip_bfloat16* __restrict__ iatt,
                                             const __hip_bfloat16* __restrict__ qatt,
                                             const bf16x8* __restrict__ B2img,
                                             const float* __restrict__ bw,
                                             const int* __restrict__ winner,
                                             float* __restrict__ outE) {
    __shared__ float s_scores[4][192];
    __shared__ int2  s_iw[4][192];       // .x = neighbor idx, .y = softmax weight bits
    const int wave = threadIdx.x >> 6, lane = threadIdx.x & 63;
    const int lo = lane & 15, hi = lane >> 4;
    const int n0 = (blockIdx.x * 4 + wave) * 8;   // grid = N_NODES/32 exactly

    // B fragments + bias/w3 from precomputed images (10 vector loads total)
    bf16x8 Bf[8];
    #pragma unroll
    for (int f = 0; f < 8; f++) Bf[f] = B2img[f * 64 + lane];
    f32x4 bb = *reinterpret_cast<const f32x4*>(bw + lane * 8);
    f32x4 wv = *reinterpret_cast<const f32x4*>(bw + lane * 8 + 4);

    // prefetch neighbor ids; stage into LDS (row r = nd*24+k == t*16+lo)
    int idxs[12], nls[12];
    #pragma unroll
    for (int t = 0; t < 12; t++) {
        int r = t * 16 + lo;
        int nl = r / 24;
        nls[t] = nl;
        idxs[t] = nidx[(size_t)(n0 + nl) * KNEI + (r - nl * 24)];
        s_iw[wave][r].x = idxs[t];
    }

    #pragma unroll
    for (int t = 0; t < 12; t++) {
        const bf16x8* iarow = reinterpret_cast<const bf16x8*>(iatt + (size_t)idxs[t] * E);
        const bf16x8* qrow  = reinterpret_cast<const bf16x8*>(qatt + (size_t)(n0 + nls[t]) * E);
        f32x4 acc[4];
        #pragma unroll
        for (int u = 0; u < 4; u++)
            acc[u] = (f32x4){bb[u], bb[u], bb[u], bb[u]};   // fold ab2 into C-init
        #pragma unroll
        for (int s = 0; s < 2; s++) {
            bf16x8 ia = iarow[4 * s + hi];
            bf16x8 qa = qrow[4 * s + hi];
            bf16x8 a;
            #pragma unroll
            for (int e = 0; e < 8; e++) {
                float v = bf2f(ia[e]) + bf2f(qa[e]);
                a[e] = f2bf(fmaxf(v, 0.f));
            }
            #pragma unroll
            for (int u = 0; u < 4; u++)
                acc[u] = __builtin_amdgcn_mfma_f32_16x16x32_bf16(a, Bf[s * 4 + u], acc[u], 0, 0, 0);
        }
        // score partial: relu(h2+b2) . aW3 over this lane's 16-col slice
        f32x4 sum;
        #pragma unroll
        for (int reg = 0; reg < 4; reg++) {
            float v = 0.f;
            #pragma unroll
            for (int u = 0; u < 4; u++)
                v = fmaf(fmaxf(acc[u][reg], 0.f), wv[u], v);
            sum[reg] = v;
        }
        #pragma unroll
        for (int m = 1; m < 16; m <<= 1) {
            #pragma unroll
            for (int reg = 0; reg < 4; reg++)
                sum[reg] += __shfl_xor(sum[reg], m);
        }
        if (lo == 0)
            *reinterpret_cast<f32x4*>(&s_scores[wave][t * 16 + hi * 4]) = sum;
    }
    __syncthreads();

    // softmax + weighted aggregation: 2 nodes in parallel (one per 32-lane half)
    const int half = lane >> 5, j = lane & 31;
    for (int p = 0; p < 4; p++) {
        int nd = 2 * p + half;
        int n = n0 + nd;
        float sc = (j < KNEI) ? s_scores[wave][nd * KNEI + j] : -1e30f;
        float mx = sc;
        #pragma unroll
        for (int m = 1; m < 32; m <<= 1) mx = fmaxf(mx, __shfl_xor(mx, m));
        float e = (j < KNEI) ? __expf(sc - mx) : 0.f;
        float ss = e;
        #pragma unroll
        for (int m = 1; m < 32; m <<= 1) ss += __shfl_xor(ss, m);
        float w = e / ss;
        if (j < KNEI) s_iw[wave][nd * KNEI + j].y = __float_as_int(w);

        float emb0 = 0.f, emb1 = 0.f;
        const char* ipb = reinterpret_cast<const char*>(iproj);
        #pragma unroll
        for (int k = 0; k < KNEI; k++) {
            int2 iw = s_iw[wave][nd * KNEI + k];      // ds_read_b64 broadcast per half
            float wk = __int_as_float(iw.y);
            unsigned u = *reinterpret_cast<const unsigned*>(
                ipb + (size_t)iw.x * 128 + j * 4);    // dims 2j, 2j+1
            emb0 = fmaf(wk, __uint_as_float(u << 16), emb0);
            emb1 = fmaf(wk, __uint_as_float(u & 0xFFFF0000u), emb1);
        }
        int un = nodes[n];
        if (winner[un] == n) {
            float2 st = make_float2(emb0, emb1);
            *reinterpret_cast<float2*>(outE + (size_t)un * E + 2 * j) = st;
        }
    }
}

extern "C" void kernel_launch(void* const* d_in, const int* in_sizes, int n_in,
                              void* d_out, int out_size, void* d_ws, size_t ws_size,
                              hipStream_t stream) {
    const int*   nodes = (const int*)d_in[0];
    const float* nfeat = (const float*)d_in[1];
    const int*   nidx  = (const int*)d_in[2];
    const float* uwt   = (const float*)d_in[3];
    const float* iwt   = (const float*)d_in[4];
    const float* uW    = (const float*)d_in[5];
    const float* ub    = (const float*)d_in[6];
    const float* iW    = (const float*)d_in[7];
    const float* ib    = (const float*)d_in[8];
    const float* aW1   = (const float*)d_in[9];
    const float* ab1   = (const float*)d_in[10];
    const float* aW2   = (const float*)d_in[11];
    const float* ab2   = (const float*)d_in[12];
    const float* aW3   = (const float*)d_in[13];
    // d_in[14] = ab3: softmax-shift-invariant, unused

    float* out_nf  = (float*)d_out;
    float* out_emb = out_nf + (size_t)N_NODES * E;

    char* ws = (char*)d_ws;
    __hip_bfloat16* iproj = (__hip_bfloat16*)(ws);
    __hip_bfloat16* iatt  = (__hip_bfloat16*)(ws + 25600000);
    __hip_bfloat16* qatt  = (__hip_bfloat16*)(ws + 51200000);
    int*            winner = (int*)(ws + 64000000);
    float*          Wp     = (float*)(ws + 64800000);
    float*          bp     = (float*)(ws + 64832768);
    bf16x8*         B2img  = (bf16x8*)(ws + 64833024);
    float*          bwimg  = (float*)(ws + 64841216);

    hipMemsetAsync(winner, 0xFF, (size_t)N_USERS * sizeof(int), stream);
    hipMemsetAsync(out_emb, 0, (size_t)N_USERS * E * sizeof(float), stream);

    k_fuse<<<34, 256, 0, stream>>>(iW, aW1, ib, ab1, aW2, ab2, aW3,
                                   Wp, bp, B2img, bwimg);
    k_item<<<512, 256, 0, stream>>>(iwt, iW, ib, Wp, bp, iproj, iatt);
    k_node1<<<256, 256, 0, stream>>>(nodes, uwt, uW, ub, out_nf, winner);
    k_node2<<<256, 256, 0, stream>>>(out_nf, nfeat, aW1, qatt);
    k_att<<<N_NODES / 32, 256, 0, stream>>>(nodes, nidx, iproj, iatt, qatt,
                                            B2img, bwimg, winner, out_emb);
}